// Round 11
// baseline (690.289 us; speedup 1.0000x reference)
//
#include <hip/hip_runtime.h>
#include <cmath>

typedef __bf16 bf16;
typedef float f32x4 __attribute__((ext_vector_type(4)));
typedef bf16 bf16x8 __attribute__((ext_vector_type(8)));
typedef bf16 bf16x4 __attribute__((ext_vector_type(4)));

#define DEV __device__ __forceinline__

DEV void gload_lds16(const void* g, void* l) {
    __builtin_amdgcn_global_load_lds(
        (const __attribute__((address_space(1))) void*)g,
        (__attribute__((address_space(3))) void*)l, 16, 0, 0);
}

// XOR swizzle for 128-byte LDS rows: spreads 8 consecutive rows across the
// 8 16B slots of a row so column-slice ds_read_b128 is conflict-free (T2).
DEV int swz(int row, int colb) { return (row * 128 + colb) ^ ((row & 7) << 4); }

// Chunked bijective XCD swizzle (m204).
DEV int xcd_chunk(int flat, int nwg) {
    int xcd = flat & 7, loc = flat >> 3;
    int q = nwg >> 3, r = nwg & 7;
    return (xcd < r ? xcd * (q + 1) : r * (q + 1) + (xcd - r) * q) + loc;
}

// 2D per-XCD GEMM block mapping: XCD owns gy/8 m-rows x all gx n-cols,
// walked in 4-wide n-strips (m-major within strip). Keeps a strip's
// working set L2-resident so staging re-reads hit L2, not L3.
DEV void map2d(int flat, int gx, int gy, int& mb, int& nb) {
    if ((gy & 7) == 0 && (gx & 3) == 0) {
        int xcd = flat & 7, loc = flat >> 3;
        int rpx = gy >> 3;
        int strip = loc / (rpx * 4);
        int t = loc % (rpx * 4);
        mb = xcd * rpx + (t >> 2);
        nb = strip * 4 + (t & 3);
    } else {
        int wg = xcd_chunk(flat, gx * gy);
        mb = wg / gx;
        nb = wg % gx;
    }
}

// 0.125 * log2(e): scores kept in scaled (exp2) units everywhere.
#define SC2 0.1803368801111244f

// ---------------------------------------------------------------------------
// fused f32 -> bf16 convert for the 6 weight blocks (contiguous outputs)
// ---------------------------------------------------------------------------
struct CvtArgs { const float* src[6]; };
__global__ __launch_bounds__(256) void wcvt_kernel(CvtArgs a, bf16* __restrict__ out) {
    const int cum[7] = {0, 786432, 1048576, 1835008, 2097152, 3145728, 4194304};
    int i = blockIdx.x * 256 + threadIdx.x;  // float4 units
    int seg = 0;
#pragma unroll
    for (int s = 1; s < 6; s++) seg += (i >= cum[s]);
    float4 v = ((const float4*)a.src[seg])[i - cum[seg]];
    bf16x4 o;
    o[0] = (bf16)v.x; o[1] = (bf16)v.y; o[2] = (bf16)v.z; o[3] = (bf16)v.w;
    ((bf16x4*)out)[i] = o;
}

// ---------------------------------------------------------------------------
// transpose 1024x1024 f32 -> bf16 (out[f][d] = in[d][f])
// ---------------------------------------------------------------------------
__global__ __launch_bounds__(256) void transpose_cvt_kernel(const float* __restrict__ in,
                                                            bf16* __restrict__ out) {
    __shared__ float tile[32][33];
    int tx = threadIdx.x, ty = threadIdx.y;
    int d0 = blockIdx.x * 32, f0 = blockIdx.y * 32;
#pragma unroll
    for (int rr = 0; rr < 4; rr++) {
        int dd = ty + rr * 8;
        tile[dd][tx] = in[(size_t)(d0 + dd) * 1024 + f0 + tx];
    }
    __syncthreads();
#pragma unroll
    for (int rr = 0; rr < 4; rr++) {
        int ff = ty + rr * 8;
        out[(size_t)(f0 + ff) * 1024 + d0 + tx] = (bf16)tile[tx][ff];
    }
}

// ---------------------------------------------------------------------------
// transpose V slice: V[b][t][voff + h*64 + d] (stride vstride) ->
// VT[(b*16+h)*64 + d][t]   (bf16 -> bf16)
// ---------------------------------------------------------------------------
__global__ __launch_bounds__(256) void transpose_v_kernel(
    const bf16* __restrict__ V, int vstride, int voff,
    bf16* __restrict__ VT, int T) {
    __shared__ bf16 tile[32][34];
    const int bh = blockIdx.z, b = bh >> 4, h = bh & 15;
    const int d0 = blockIdx.y * 32, t0 = blockIdx.x * 32;
    const int tx = threadIdx.x, ty = threadIdx.y;
#pragma unroll
    for (int rr = 0; rr < 4; rr++) {
        int t = ty + rr * 8;
        tile[t][tx] = V[(size_t)(b * T + t0 + t) * vstride + voff + h * 64 + d0 + tx];
    }
    __syncthreads();
#pragma unroll
    for (int rr = 0; rr < 4; rr++) {
        int d = ty + rr * 8;
        VT[(size_t)(bh * 64 + d0 + d) * T + t0 + tx] = tile[tx][d];
    }
}

// ---------------------------------------------------------------------------
// LayerNorm over rows of 1024 f32 -> bf16   (gamma/beta f32)
// ---------------------------------------------------------------------------
__global__ __launch_bounds__(256) void ln_kernel(const float* __restrict__ x,
                                                 const float* __restrict__ gw,
                                                 const float* __restrict__ bw,
                                                 bf16* __restrict__ y) {
    int row = blockIdx.x, tid = threadIdx.x;
    const float4 v = *(const float4*)(x + (size_t)row * 1024 + tid * 4);
    float s = v.x + v.y + v.z + v.w;
    float sq = v.x * v.x + v.y * v.y + v.z * v.z + v.w * v.w;
#pragma unroll
    for (int off = 1; off < 64; off <<= 1) {
        s += __shfl_xor(s, off);
        sq += __shfl_xor(sq, off);
    }
    __shared__ float ls[4], lq[4];
    if ((tid & 63) == 0) { ls[tid >> 6] = s; lq[tid >> 6] = sq; }
    __syncthreads();
    s = ls[0] + ls[1] + ls[2] + ls[3];
    sq = lq[0] + lq[1] + lq[2] + lq[3];
    float mean = s * (1.f / 1024.f);
    float var = sq * (1.f / 1024.f) - mean * mean;
    float inv = rsqrtf(var + 1e-6f);
    const float4 gv = *(const float4*)(gw + tid * 4);
    const float4 bv = *(const float4*)(bw + tid * 4);
    bf16x4 o;
    o[0] = (bf16)((v.x - mean) * inv * gv.x + bv.x);
    o[1] = (bf16)((v.y - mean) * inv * gv.y + bv.y);
    o[2] = (bf16)((v.z - mean) * inv * gv.z + bv.z);
    o[3] = (bf16)((v.w - mean) * inv * gv.w + bv.w);
    *(bf16x4*)(y + (size_t)row * 1024 + tid * 4) = o;
}

// ---------------------------------------------------------------------------
// row L2-norm of [4096,1024] f32 -> [4096] f32
// ---------------------------------------------------------------------------
__global__ __launch_bounds__(256) void rownorm_kernel(const float* __restrict__ x,
                                                      float* __restrict__ out) {
    int row = blockIdx.x, tid = threadIdx.x;
    const float4 v = *(const float4*)(x + (size_t)row * 1024 + tid * 4);
    float sq = v.x * v.x + v.y * v.y + v.z * v.z + v.w * v.w;
#pragma unroll
    for (int off = 1; off < 64; off <<= 1) sq += __shfl_xor(sq, off);
    __shared__ float ls[4];
    if ((tid & 63) == 0) ls[tid >> 6] = sq;
    __syncthreads();
    if (tid == 0) out[row] = sqrtf(ls[0] + ls[1] + ls[2] + ls[3]);
}

// ---------------------------------------------------------------------------
// bf16 MFMA GEMM:  C[M,N] = A[M,K] * W[N,K]^T (+bias[N]) (gelu) (+resid[M,N])
// BM x 128 tile, BK=64, 4 waves. Both-sides LDS XOR swizzle (T2, rule #21).
// DB=1: 2-phase double-buffer prefetch. 2D per-XCD mapping (map2d) keeps the
// staging working set L2-resident. Writes f32 (Cf) and/or bf16 (Cb).
// ---------------------------------------------------------------------------
template <int BM, int DB>
__global__ __launch_bounds__(256) void gemm_k(
    const bf16* __restrict__ A, const bf16* __restrict__ W,
    const float* __restrict__ bias, const float* __restrict__ resid,
    float* __restrict__ Cf, bf16* __restrict__ Cb,
    int M, int N, int K, int act_gelu) {
    constexpr int RA = BM * 64 / 2048;       // gload reps for A tile
    constexpr int RB = 4;                    // 128*64/2048
    constexpr int NI = (BM == 128) ? 4 : 2;  // col frags per wave
    constexpr int WC = (BM == 128) ? 64 : 32;
    __shared__ __align__(16) bf16 lA[(DB + 1) * BM * 64];
    __shared__ __align__(16) bf16 lB[(DB + 1) * 128 * 64];
    const int tid = threadIdx.x;
    const int lane = tid & 63, w = tid >> 6;
    const int wr = (BM == 128) ? (w >> 1) : 0;
    const int wc = (BM == 128) ? (w & 1) : w;
    const int g = lane >> 4, fr = lane & 15;
    int mb, nb;
    map2d(blockIdx.y * gridDim.x + blockIdx.x, gridDim.x, gridDim.y, mb, nb);
    const int m0 = mb * BM, n0 = nb * 128;

    f32x4 acc[4][NI];
#pragma unroll
    for (int i = 0; i < 4; i++)
#pragma unroll
        for (int j = 0; j < NI; j++)
#pragma unroll
            for (int r = 0; r < 4; r++) acc[i][j][r] = 0.f;

    const int e0 = tid * 8;
    auto STAGE = [&](int buf, int kt) {
#pragma unroll
        for (int rep = 0; rep < RA; rep++) {
            int e = e0 + rep * 2048;
            int r = e >> 6, c = e & 63;
            int cs = c ^ ((r & 7) << 3);  // inverse-swizzled source column
            gload_lds16(A + (size_t)(m0 + r) * K + kt + cs, &lA[buf * BM * 64 + e]);
        }
#pragma unroll
        for (int rep = 0; rep < RB; rep++) {
            int e = e0 + rep * 2048;
            int r = e >> 6, c = e & 63;
            int cs = c ^ ((r & 7) << 3);
            gload_lds16(W + (size_t)(n0 + r) * K + kt + cs, &lB[buf * 128 * 64 + e]);
        }
    };

    int cur = 0;
    if (DB) { STAGE(0, 0); __syncthreads(); }
    for (int kt = 0; kt < K; kt += 64) {
        if (DB) {
            if (kt + 64 < K) STAGE(cur ^ 1, kt + 64);
        } else {
            STAGE(0, kt);
            __syncthreads();
        }
        const char* bA = (const char*)lA + cur * (BM * 128);
        const char* bB = (const char*)lB + cur * (128 * 128);
        bf16x8 af[2][4], bfr[2][NI];
#pragma unroll
        for (int kk = 0; kk < 2; kk++) {
#pragma unroll
            for (int mi = 0; mi < 4; mi++)
                af[kk][mi] = *(const bf16x8*)(bA + swz(wr * 64 + mi * 16 + fr, kk * 64 + g * 16));
#pragma unroll
            for (int ni = 0; ni < NI; ni++)
                bfr[kk][ni] = *(const bf16x8*)(bB + swz(wc * WC + ni * 16 + fr, kk * 64 + g * 16));
        }
#pragma unroll
        for (int kk = 0; kk < 2; kk++)
#pragma unroll
            for (int mi = 0; mi < 4; mi++)
#pragma unroll
                for (int ni = 0; ni < NI; ni++)
                    acc[mi][ni] = __builtin_amdgcn_mfma_f32_16x16x32_bf16(
                        af[kk][mi], bfr[kk][ni], acc[mi][ni], 0, 0, 0);
        __syncthreads();
        if (DB) cur ^= 1;
    }
#pragma unroll
    for (int ni = 0; ni < NI; ni++) {
        const int col = n0 + wc * WC + ni * 16 + fr;
        const float bv = bias ? bias[col] : 0.f;
#pragma unroll
        for (int mi = 0; mi < 4; mi++) {
#pragma unroll
            for (int r = 0; r < 4; r++) {
                const int row = m0 + wr * 64 + mi * 16 + g * 4 + r;
                float v = acc[mi][ni][r] + bv;
                if (act_gelu) v = 0.5f * v * (1.f + erff(v * 0.70710678118654752f));
                if (resid) v += resid[(size_t)row * N + col];
                if (Cb) Cb[(size_t)row * N + col] = (bf16)v;
                if (Cf) Cf[(size_t)row * N + col] = v;
            }
        }
    }
}

// ---------------------------------------------------------------------------
// Flash attention. 4 waves x 16 q-rows, KV tiles of 64. Double-buffered LDS
// staged via global_load_lds with PRE-SWIZZLED source columns (rule #21):
// LDS dest is linear (base + lane*16); source col16 = c16 ^ (row&7), which
// reproduces the swz() content so compute-side reads are unchanged.
// Next tile's staging issues before compute; one barrier per tile drains it.
// l-sum via MFMA against all-ones B. exp2 domain.
// ---------------------------------------------------------------------------
__global__ __launch_bounds__(256) void flash_kernel(
    const bf16* __restrict__ Qb, int qs, const bf16* __restrict__ Kb, int ks,
    const bf16* __restrict__ VT, bf16* __restrict__ Ob, int os,
    float* __restrict__ m_out, float* __restrict__ l_out,
    int T, int S, int causal) {
    __shared__ __align__(16) char Kl[2][64 * 128];
    __shared__ __align__(16) char Vl[2][64 * 128];
    __shared__ __align__(16) char Pl[4][16 * 128];

    const int tid = threadIdx.x;
    const int lane = tid & 63, w = tid >> 6;
    const int g = lane >> 4, fr = lane & 15;
    const int gx = gridDim.x;
    const int wg = xcd_chunk(blockIdx.y * gx + blockIdx.x, gx * gridDim.y);
    const int tblk = wg % gx;
    const int bh = wg / gx, b = bh >> 4, h = bh & 15;
    const int t0 = tblk * 64 + w * 16;

    const bf16* Q = Qb + (size_t)h * 64;
    const bf16* K = Kb + (size_t)h * 64;

    bf16x8 qf[2];
    {
        const bf16* qrow = Q + (size_t)(b * T + t0 + fr) * qs + g * 8;
        qf[0] = *(const bf16x8*)(qrow);
        qf[1] = *(const bf16x8*)(qrow + 32);
    }
    bf16x8 onef;
#pragma unroll
    for (int j = 0; j < 8; j++) onef[j] = (bf16)1.f;

    float m_r[4];
    f32x4 lsum;
    f32x4 o[4];
#pragma unroll
    for (int r = 0; r < 4; r++) { m_r[r] = -1e30f; lsum[r] = 0.f; }
#pragma unroll
    for (int d = 0; d < 4; d++)
#pragma unroll
        for (int r = 0; r < 4; r++) o[d][r] = 0.f;

    const int l8 = lane >> 3, c16 = lane & 7;
    auto STAGE = [&](int buf, int s0) {
#pragma unroll
        for (int rp = 0; rp < 2; rp++) {
            const int r0 = rp * 32 + w * 8;
            const int r = r0 + l8;
            const int cs = (c16 ^ (r & 7)) * 8;  // pre-swizzled source col (elems)
            gload_lds16(K + (size_t)(b * S + s0 + r) * ks + cs,
                        Kl[buf] + r0 * 128 + lane * 16);
            gload_lds16(VT + (size_t)(bh * 64 + r) * S + s0 + cs,
                        Vl[buf] + r0 * 128 + lane * 16);
        }
    };

    // prologue: stage tile 0 into buf 0
    STAGE(0, 0);
    __syncthreads();

    const int nkb = causal ? (tblk + 1) : (S >> 6);
    int cur = 0;
    for (int kb = 0; kb < nkb; kb++) {
        const int s0 = kb * 64;
        if (kb + 1 < nkb) STAGE(cur ^ 1, s0 + 64);  // fire-and-forget prefetch

        float p[4][4];
#pragma unroll
        for (int sf = 0; sf < 4; sf++) {
            bf16x8 kf0 = *(const bf16x8*)(Kl[cur] + swz(sf * 16 + fr, g * 16));
            bf16x8 kf1 = *(const bf16x8*)(Kl[cur] + swz(sf * 16 + fr, 64 + g * 16));
            f32x4 sa;
            sa[0] = sa[1] = sa[2] = sa[3] = 0.f;
            sa = __builtin_amdgcn_mfma_f32_16x16x32_bf16(qf[0], kf0, sa, 0, 0, 0);
            sa = __builtin_amdgcn_mfma_f32_16x16x32_bf16(qf[1], kf1, sa, 0, 0, 0);
#pragma unroll
            for (int r = 0; r < 4; r++) {
                float sc = sa[r] * SC2;
                if (causal) {
                    int t = t0 + g * 4 + r, s = s0 + sf * 16 + fr;
                    if (s > t) sc = -1e30f;
                }
                p[sf][r] = sc;
            }
        }
        float mb[4], corr[4];
#pragma unroll
        for (int r = 0; r < 4; r++) {
            mb[r] = fmaxf(fmaxf(p[0][r], p[1][r]), fmaxf(p[2][r], p[3][r]));
            mb[r] = fmaxf(mb[r], __shfl_xor(mb[r], 1));
            mb[r] = fmaxf(mb[r], __shfl_xor(mb[r], 2));
            mb[r] = fmaxf(mb[r], __shfl_xor(mb[r], 4));
            mb[r] = fmaxf(mb[r], __shfl_xor(mb[r], 8));
            float mn = fmaxf(m_r[r], mb[r]);
            corr[r] = exp2f(m_r[r] - mn);
            m_r[r] = mn;
        }
#pragma unroll
        for (int sf = 0; sf < 4; sf++)
#pragma unroll
            for (int r = 0; r < 4; r++)
                p[sf][r] = exp2f(p[sf][r] - m_r[r]);
#pragma unroll
        for (int r = 0; r < 4; r++) lsum[r] *= corr[r];
#pragma unroll
        for (int d = 0; d < 4; d++)
#pragma unroll
            for (int r = 0; r < 4; r++) o[d][r] *= corr[r];
#pragma unroll
        for (int sf = 0; sf < 4; sf++)
#pragma unroll
            for (int r = 0; r < 4; r++)
                *(bf16*)(Pl[w] + swz(g * 4 + r, (sf * 16 + fr) * 2)) = (bf16)p[sf][r];
#pragma unroll
        for (int kc = 0; kc < 2; kc++) {
            bf16x8 pf = *(const bf16x8*)(Pl[w] + swz(fr, kc * 64 + g * 16));
            lsum = __builtin_amdgcn_mfma_f32_16x16x32_bf16(pf, onef, lsum, 0, 0, 0);
#pragma unroll
            for (int d = 0; d < 4; d++) {
                bf16x8 vf = *(const bf16x8*)(Vl[cur] + swz(d * 16 + fr, kc * 64 + g * 16));
                o[d] = __builtin_amdgcn_mfma_f32_16x16x32_bf16(pf, vf, o[d], 0, 0, 0);
            }
        }
        __syncthreads();   // drains prefetch vmcnt; next buf ready
        cur ^= 1;
    }

    float inv[4];
#pragma unroll
    for (int r = 0; r < 4; r++) inv[r] = __builtin_amdgcn_rcpf(lsum[r]);
#pragma unroll
    for (int d = 0; d < 4; d++)
#pragma unroll
        for (int r = 0; r < 4; r++) {
            int t = t0 + g * 4 + r;
            Ob[((size_t)(b * T + t)) * os + h * 64 + d * 16 + fr] =
                (bf16)(o[d][r] * inv[r]);
        }
    if (m_out && fr == 0) {
#pragma unroll
        for (int r = 0; r < 4; r++) {
            int t = t0 + g * 4 + r;
            m_out[((size_t)(b * 16 + h)) * T + t] = m_r[r];   // exp2-scaled units
            l_out[((size_t)(b * 16 + h)) * T + t] = lsum[r];
        }
    }
}

// ---------------------------------------------------------------------------
// Cross-attn probs mean over heads * ||tv||:  out1[b,t,s].
// No LDS, no barriers; 64t x 32s tiles (grid 2048 = 8 blocks/CU) so TLP
// hides the per-h load-latency chain. 16-h loop.
// ---------------------------------------------------------------------------
__global__ __launch_bounds__(256) void probsmean_kernel(
    const bf16* __restrict__ Qb, const bf16* __restrict__ Kb,
    const float* __restrict__ m_arr, const float* __restrict__ l_arr,
    const float* __restrict__ norms, float* __restrict__ outw, int T, int S) {
    const int tid = threadIdx.x;
    const int lane = tid & 63, w = tid >> 6;
    const int g = lane >> 4, fr = lane & 15;
    const int flat = (blockIdx.z * gridDim.y + blockIdx.y) * gridDim.x + blockIdx.x;
    const int wg = xcd_chunk(flat, gridDim.x * gridDim.y * gridDim.z);
    const int tblk = wg & 15, sblk = (wg >> 4) & 31, b = wg >> 9;
    const int t0 = tblk * 64 + w * 16;
    const int s0 = sblk * 32;

    float acc[2][4];
#pragma unroll
    for (int sf = 0; sf < 2; sf++)
#pragma unroll
        for (int r = 0; r < 4; r++) acc[sf][r] = 0.f;

    const bf16* qbase = Qb + ((size_t)(b * T + t0 + fr)) * 1024 + g * 8;
    const bf16* kbase = Kb + ((size_t)(b * S + s0 + fr)) * 2048 + g * 8;

    for (int h = 0; h < 16; h++) {
        const int hoff = h * 64;
        bf16x8 qf0 = *(const bf16x8*)(qbase + hoff);
        bf16x8 qf1 = *(const bf16x8*)(qbase + hoff + 32);
        bf16x8 kf0[2], kf1[2];
#pragma unroll
        for (int sf = 0; sf < 2; sf++) {
            const bf16* krow = kbase + (size_t)sf * 16 * 2048 + hoff;
            kf0[sf] = *(const bf16x8*)(krow);
            kf1[sf] = *(const bf16x8*)(krow + 32);
        }
        float mh[4], il[4];
#pragma unroll
        for (int r = 0; r < 4; r++) {
            int t = t0 + g * 4 + r;
            mh[r] = m_arr[((size_t)(b * 16 + h)) * T + t];
            il[r] = __builtin_amdgcn_rcpf(l_arr[((size_t)(b * 16 + h)) * T + t] * 16.f);
        }
#pragma unroll
        for (int sf = 0; sf < 2; sf++) {
            f32x4 sa;
            sa[0] = sa[1] = sa[2] = sa[3] = 0.f;
            sa = __builtin_amdgcn_mfma_f32_16x16x32_bf16(qf0, kf0[sf], sa, 0, 0, 0);
            sa = __builtin_amdgcn_mfma_f32_16x16x32_bf16(qf1, kf1[sf], sa, 0, 0, 0);
#pragma unroll
            for (int r = 0; r < 4; r++)
                acc[sf][r] += exp2f(sa[r] * SC2 - mh[r]) * il[r];
        }
    }
#pragma unroll
    for (int sf = 0; sf < 2; sf++) {
        int s = s0 + sf * 16 + fr;
        float nr = norms[b * S + s];
#pragma unroll
        for (int r = 0; r < 4; r++) {
            int t = t0 + g * 4 + r;
            outw[((size_t)(b * T + t)) * S + s] = acc[sf][r] * nr;
        }
    }
}

// ---------------------------------------------------------------------------
extern "C" void kernel_launch(void* const* d_in, const int* in_sizes, int n_in,
                              void* d_out, int out_size, void* d_ws, size_t ws_size,
                              hipStream_t stream) {
    (void)in_sizes; (void)n_in; (void)out_size; (void)ws_size;
    const float* decoder_input  = (const float*)d_in[0];
    const float* encoder_output = (const float*)d_in[1];
    const float* ln_g   = (const float*)d_in[4];
    const float* ln_b   = (const float*)d_in[5];
    const float* w_in1  = (const float*)d_in[6];
    const float* b_in1  = (const float*)d_in[7];
    const float* w_out1 = (const float*)d_in[8];
    const float* b_out1 = (const float*)d_in[9];
    const float* w_in2  = (const float*)d_in[10];
    const float* b_in2  = (const float*)d_in[11];
    const float* w_out2 = (const float*)d_in[12];
    const float* b_out2 = (const float*)d_in[13];
    const float* mlp_w1 = (const float*)d_in[14];
    const float* mlp_b1 = (const float*)d_in[15];
    const float* mlp_w2 = (const float*)d_in[16];
    const float* mlp_b2 = (const float*)d_in[17];

    char* ws = (char*)d_ws;
    size_t off = 0;
    auto alloc = [&](size_t bytes) {
        char* p = ws + off;
        off += (bytes + 255) & ~(size_t)255;
        return p;
    };
    // Six cvt outputs contiguous (all sizes are 256B multiples -> no padding):
    bf16* W_IN1B   = (bf16*)alloc(3072ULL * 1024 * 2);
    bf16* W_OUT1B  = (bf16*)alloc(1024ULL * 1024 * 2);
    bf16* W_IN2B   = (bf16*)alloc(3072ULL * 1024 * 2);
    bf16* W_OUT2B  = (bf16*)alloc(1024ULL * 1024 * 2);
    bf16* MLPW1B   = (bf16*)alloc(4096ULL * 1024 * 2);
    bf16* MLPW2B   = (bf16*)alloc(4096ULL * 1024 * 2);
    bf16* W_OUT2TB = (bf16*)alloc(1024ULL * 1024 * 2);
    char* REGION_QKV = alloc(4096ULL * 3072 * 2);   // qkv1; later q2 + kv2
    char* REGION_H   = alloc(4096ULL * 4096 * 2);   // de_in_b; later tv(f32); later h
    bf16*  ATTNB  = (bf16*)alloc(4096ULL * 1024 * 2);
    float* XF     = (float*)alloc(4096ULL * 1024 * 4);  // x; later lnx_b
    bf16*  XB     = (bf16*)alloc(4096ULL * 1024 * 2);
    bf16*  ENOUTB = (bf16*)alloc(4096ULL * 1024 * 2);
    float* X2F    = (float*)alloc(4096ULL * 1024 * 4);
    bf16*  VTB    = (bf16*)alloc(64ULL * 64 * 1024 * 2); // V^T per (b,h): 8MB
    float* NORMS  = (float*)alloc(4096 * 4);
    float* MARR   = (float*)alloc(65536ULL * 4);
    float* LARR   = (float*)alloc(65536ULL * 4);

    bf16* QKV1B = (bf16*)REGION_QKV;
    bf16* Q2B   = (bf16*)REGION_QKV;
    bf16* KV2B  = (bf16*)(REGION_QKV + 4096ULL * 1024 * 2);
    bf16* DEINB = (bf16*)REGION_H;
    float* TVF  = (float*)REGION_H;
    bf16* HB    = (bf16*)REGION_H;
    bf16* LNXB  = (bf16*)XF;

    float* out0 = (float*)d_out;
    float* out1 = out0 + 4ULL * 1024 * 1024;

    // fused weight conversions (6 blocks -> contiguous outputs at W_IN1B)
    CvtArgs ca;
    ca.src[0] = w_in1;  ca.src[1] = w_out1; ca.src[2] = w_in2;
    ca.src[3] = w_out2; ca.src[4] = mlp_w1; ca.src[5] = mlp_w2;
    wcvt_kernel<<<16384, 256, 0, stream>>>(ca, W_IN1B);
    transpose_cvt_kernel<<<dim3(32, 32), dim3(32, 8), 0, stream>>>(w_out2, W_OUT2TB);

    // de_in = LN(decoder_input)
    ln_kernel<<<4096, 256, 0, stream>>>(decoder_input, ln_g, ln_b, DEINB);
    // qkv1 = de_in @ w_in1^T + b_in1
    gemm_k<128, 1><<<dim3(24, 32), 256, 0, stream>>>(
        DEINB, W_IN1B, b_in1, nullptr, nullptr, QKV1B, 4096, 3072, 1024, 0);
    // self attention (causal): pre-transpose V, then flash
    transpose_v_kernel<<<dim3(32, 2, 64), dim3(32, 8), 0, stream>>>(
        QKV1B + 2048, 3072, 0, VTB, 1024);
    flash_kernel<<<dim3(16, 64), 256, 0, stream>>>(
        QKV1B, 3072, QKV1B + 1024, 3072, VTB, ATTNB, 1024,
        nullptr, nullptr, 1024, 1024, 1);
    // x = decoder_input + attn @ w_out1^T + b_out1  (write f32 + bf16)
    gemm_k<64, 1><<<dim3(8, 64), 256, 0, stream>>>(
        ATTNB, W_OUT1B, b_out1, decoder_input, XF, XB, 4096, 1024, 1024, 0);
    // en_out = LN(encoder_output)
    ln_kernel<<<4096, 256, 0, stream>>>(encoder_output, ln_g, ln_b, ENOUTB);
    // q2 = x @ wq2^T + bq2 ; kv2 = en_out @ w{k,v}2^T + b{k,v}2
    gemm_k<64, 1><<<dim3(8, 64), 256, 0, stream>>>(
        XB, W_IN2B, b_in2, nullptr, nullptr, Q2B, 4096, 1024, 1024, 0);
    gemm_k<128, 1><<<dim3(16, 32), 256, 0, stream>>>(
        ENOUTB, W_IN2B + 1024ULL * 1024, b_in2 + 1024, nullptr, nullptr, KV2B,
        4096, 2048, 1024, 0);
    // cross attention (stores m,l): pre-transpose V2, then flash
    transpose_v_kernel<<<dim3(32, 2, 64), dim3(32, 8), 0, stream>>>(
        KV2B + 1024, 2048, 0, VTB, 1024);
    flash_kernel<<<dim3(16, 64), 256, 0, stream>>>(
        Q2B, 1024, KV2B, 2048, VTB, ATTNB, 1024, MARR, LARR,
        1024, 1024, 0);
    // x2 = x + attn2 @ w_out2^T + b_out2
    gemm_k<64, 1><<<dim3(8, 64), 256, 0, stream>>>(
        ATTNB, W_OUT2B, b_out2, XF, X2F, nullptr, 4096, 1024, 1024, 0);
    // tv = en_out @ w_out2 (non-transposed) -> row norms
    gemm_k<64, 1><<<dim3(8, 64), 256, 0, stream>>>(
        ENOUTB, W_OUT2TB, nullptr, nullptr, TVF, nullptr, 4096, 1024, 1024, 0);
    rownorm_kernel<<<4096, 256, 0, stream>>>(TVF, NORMS);
    // out1 = mean_h(probs) * ||tv||
    probsmean_kernel<<<dim3(16, 32, 4), 256, 0, stream>>>(
        Q2B, KV2B, MARR, LARR, NORMS, out1, 1024, 1024);
    // mlp
    ln_kernel<<<4096, 256, 0, stream>>>(X2F, ln_g, ln_b, LNXB);
    gemm_k<128, 1><<<dim3(32, 32), 256, 0, stream>>>(
        LNXB, MLPW1B, mlp_b1, nullptr, nullptr, HB, 4096, 4096, 1024, 1);
    gemm_k<64, 1><<<dim3(8, 64), 256, 0, stream>>>(
        HB, MLPW2B, mlp_b2, X2F, out0, nullptr, 4096, 1024, 4096, 0);
}

// Round 12
// 638.123 us; speedup vs baseline: 1.0817x; 1.0817x over previous
//
#include <hip/hip_runtime.h>
#include <cmath>

typedef __bf16 bf16;
typedef float f32x4 __attribute__((ext_vector_type(4)));
typedef bf16 bf16x8 __attribute__((ext_vector_type(8)));
typedef bf16 bf16x4 __attribute__((ext_vector_type(4)));

#define DEV __device__ __forceinline__

DEV void gload_lds16(const void* g, void* l) {
    __builtin_amdgcn_global_load_lds(
        (const __attribute__((address_space(1))) void*)g,
        (__attribute__((address_space(3))) void*)l, 16, 0, 0);
}

// XOR swizzle for 128-byte LDS rows: spreads 8 consecutive rows across the
// 8 16B slots of a row so column-slice ds_read_b128 is conflict-free (T2).
DEV int swz(int row, int colb) { return (row * 128 + colb) ^ ((row & 7) << 4); }

// Chunked bijective XCD swizzle (m204).
DEV int xcd_chunk(int flat, int nwg) {
    int xcd = flat & 7, loc = flat >> 3;
    int q = nwg >> 3, r = nwg & 7;
    return (xcd < r ? xcd * (q + 1) : r * (q + 1) + (xcd - r) * q) + loc;
}

// 2D per-XCD GEMM block mapping: XCD owns gy/8 m-rows x all gx n-cols,
// walked in 4-wide n-strips (m-major within strip). Keeps a strip's
// working set L2-resident so staging re-reads hit L2, not L3.
DEV void map2d(int flat, int gx, int gy, int& mb, int& nb) {
    if ((gy & 7) == 0 && (gx & 3) == 0) {
        int xcd = flat & 7, loc = flat >> 3;
        int rpx = gy >> 3;
        int strip = loc / (rpx * 4);
        int t = loc % (rpx * 4);
        mb = xcd * rpx + (t >> 2);
        nb = strip * 4 + (t & 3);
    } else {
        int wg = xcd_chunk(flat, gx * gy);
        mb = wg / gx;
        nb = wg % gx;
    }
}

// 0.125 * log2(e): scores kept in scaled (exp2) units everywhere.
#define SC2 0.1803368801111244f

// ---------------------------------------------------------------------------
// fused f32 -> bf16 convert for the 6 weight blocks (contiguous outputs)
// ---------------------------------------------------------------------------
struct CvtArgs { const float* src[6]; };
__global__ __launch_bounds__(256) void wcvt_kernel(CvtArgs a, bf16* __restrict__ out) {
    const int cum[7] = {0, 786432, 1048576, 1835008, 2097152, 3145728, 4194304};
    int i = blockIdx.x * 256 + threadIdx.x;  // float4 units
    int seg = 0;
#pragma unroll
    for (int s = 1; s < 6; s++) seg += (i >= cum[s]);
    float4 v = ((const float4*)a.src[seg])[i - cum[seg]];
    bf16x4 o;
    o[0] = (bf16)v.x; o[1] = (bf16)v.y; o[2] = (bf16)v.z; o[3] = (bf16)v.w;
    ((bf16x4*)out)[i] = o;
}

// ---------------------------------------------------------------------------
// transpose 1024x1024 f32 -> bf16 (out[f][d] = in[d][f])
// ---------------------------------------------------------------------------
__global__ __launch_bounds__(256) void transpose_cvt_kernel(const float* __restrict__ in,
                                                            bf16* __restrict__ out) {
    __shared__ float tile[32][33];
    int tx = threadIdx.x, ty = threadIdx.y;
    int d0 = blockIdx.x * 32, f0 = blockIdx.y * 32;
#pragma unroll
    for (int rr = 0; rr < 4; rr++) {
        int dd = ty + rr * 8;
        tile[dd][tx] = in[(size_t)(d0 + dd) * 1024 + f0 + tx];
    }
    __syncthreads();
#pragma unroll
    for (int rr = 0; rr < 4; rr++) {
        int ff = ty + rr * 8;
        out[(size_t)(f0 + ff) * 1024 + d0 + tx] = (bf16)tile[tx][ff];
    }
}

// ---------------------------------------------------------------------------
// transpose V slice: V[b][t][voff + h*64 + d] (stride vstride) ->
// VT[(b*16+h)*64 + d][t]   (bf16 -> bf16)
// ---------------------------------------------------------------------------
__global__ __launch_bounds__(256) void transpose_v_kernel(
    const bf16* __restrict__ V, int vstride, int voff,
    bf16* __restrict__ VT, int T) {
    __shared__ bf16 tile[32][34];
    const int bh = blockIdx.z, b = bh >> 4, h = bh & 15;
    const int d0 = blockIdx.y * 32, t0 = blockIdx.x * 32;
    const int tx = threadIdx.x, ty = threadIdx.y;
#pragma unroll
    for (int rr = 0; rr < 4; rr++) {
        int t = ty + rr * 8;
        tile[t][tx] = V[(size_t)(b * T + t0 + t) * vstride + voff + h * 64 + d0 + tx];
    }
    __syncthreads();
#pragma unroll
    for (int rr = 0; rr < 4; rr++) {
        int d = ty + rr * 8;
        VT[(size_t)(bh * 64 + d0 + d) * T + t0 + tx] = tile[tx][d];
    }
}

// ---------------------------------------------------------------------------
// LayerNorm over rows of 1024 f32 -> bf16   (gamma/beta f32)
// ---------------------------------------------------------------------------
__global__ __launch_bounds__(256) void ln_kernel(const float* __restrict__ x,
                                                 const float* __restrict__ gw,
                                                 const float* __restrict__ bw,
                                                 bf16* __restrict__ y) {
    int row = blockIdx.x, tid = threadIdx.x;
    const float4 v = *(const float4*)(x + (size_t)row * 1024 + tid * 4);
    float s = v.x + v.y + v.z + v.w;
    float sq = v.x * v.x + v.y * v.y + v.z * v.z + v.w * v.w;
#pragma unroll
    for (int off = 1; off < 64; off <<= 1) {
        s += __shfl_xor(s, off);
        sq += __shfl_xor(sq, off);
    }
    __shared__ float ls[4], lq[4];
    if ((tid & 63) == 0) { ls[tid >> 6] = s; lq[tid >> 6] = sq; }
    __syncthreads();
    s = ls[0] + ls[1] + ls[2] + ls[3];
    sq = lq[0] + lq[1] + lq[2] + lq[3];
    float mean = s * (1.f / 1024.f);
    float var = sq * (1.f / 1024.f) - mean * mean;
    float inv = rsqrtf(var + 1e-6f);
    const float4 gv = *(const float4*)(gw + tid * 4);
    const float4 bv = *(const float4*)(bw + tid * 4);
    bf16x4 o;
    o[0] = (bf16)((v.x - mean) * inv * gv.x + bv.x);
    o[1] = (bf16)((v.y - mean) * inv * gv.y + bv.y);
    o[2] = (bf16)((v.z - mean) * inv * gv.z + bv.z);
    o[3] = (bf16)((v.w - mean) * inv * gv.w + bv.w);
    *(bf16x4*)(y + (size_t)row * 1024 + tid * 4) = o;
}

// ---------------------------------------------------------------------------
// row L2-norm of [4096,1024] f32 -> [4096] f32
// ---------------------------------------------------------------------------
__global__ __launch_bounds__(256) void rownorm_kernel(const float* __restrict__ x,
                                                      float* __restrict__ out) {
    int row = blockIdx.x, tid = threadIdx.x;
    const float4 v = *(const float4*)(x + (size_t)row * 1024 + tid * 4);
    float sq = v.x * v.x + v.y * v.y + v.z * v.z + v.w * v.w;
#pragma unroll
    for (int off = 1; off < 64; off <<= 1) sq += __shfl_xor(sq, off);
    __shared__ float ls[4];
    if ((tid & 63) == 0) ls[tid >> 6] = sq;
    __syncthreads();
    if (tid == 0) out[row] = sqrtf(ls[0] + ls[1] + ls[2] + ls[3]);
}

// ---------------------------------------------------------------------------
// bf16 MFMA GEMM:  C[M,N] = A[M,K] * W[N,K]^T (+bias[N]) (gelu) (+resid[M,N])
// BM x 128 tile, BK=64, 4 waves. Both-sides LDS XOR swizzle (T2, rule #21).
// DB=1: 2-phase double-buffer prefetch. map2d keeps staging L2-resident.
// bf16-only outputs take a vectorized epilogue: acc -> LDS (pitch 136) ->
// coalesced bf16x8 stores (replaces 32-64 scalar 2B stores per lane).
// ---------------------------------------------------------------------------
template <int BM, int DB>
__global__ __launch_bounds__(256) void gemm_k(
    const bf16* __restrict__ A, const bf16* __restrict__ W,
    const float* __restrict__ bias, const float* __restrict__ resid,
    float* __restrict__ Cf, bf16* __restrict__ Cb,
    int M, int N, int K, int act_gelu) {
    constexpr int RA = BM * 64 / 2048;       // gload reps for A tile
    constexpr int RB = 4;                    // 128*64/2048
    constexpr int NI = (BM == 128) ? 4 : 2;  // col frags per wave
    constexpr int WC = (BM == 128) ? 64 : 32;
    constexpr int ABYTES = (DB + 1) * BM * 64 * 2;
    constexpr int BBYTES = (DB + 1) * 128 * 64 * 2;
    constexpr int EBYTES = BM * 136 * 2;
    constexpr int SMB = (ABYTES + BBYTES) > EBYTES ? (ABYTES + BBYTES) : EBYTES;
    __shared__ __align__(16) char SM[SMB];
    bf16* lA = (bf16*)SM;
    bf16* lB = (bf16*)(SM + ABYTES);
    const int tid = threadIdx.x;
    const int lane = tid & 63, w = tid >> 6;
    const int wr = (BM == 128) ? (w >> 1) : 0;
    const int wc = (BM == 128) ? (w & 1) : w;
    const int g = lane >> 4, fr = lane & 15;
    int mb, nb;
    map2d(blockIdx.y * gridDim.x + blockIdx.x, gridDim.x, gridDim.y, mb, nb);
    const int m0 = mb * BM, n0 = nb * 128;

    f32x4 acc[4][NI];
#pragma unroll
    for (int i = 0; i < 4; i++)
#pragma unroll
        for (int j = 0; j < NI; j++)
#pragma unroll
            for (int r = 0; r < 4; r++) acc[i][j][r] = 0.f;

    const int e0 = tid * 8;
    auto STAGE = [&](int buf, int kt) {
#pragma unroll
        for (int rep = 0; rep < RA; rep++) {
            int e = e0 + rep * 2048;
            int r = e >> 6, c = e & 63;
            int cs = c ^ ((r & 7) << 3);  // inverse-swizzled source column
            gload_lds16(A + (size_t)(m0 + r) * K + kt + cs, lA + buf * BM * 64 + e);
        }
#pragma unroll
        for (int rep = 0; rep < RB; rep++) {
            int e = e0 + rep * 2048;
            int r = e >> 6, c = e & 63;
            int cs = c ^ ((r & 7) << 3);
            gload_lds16(W + (size_t)(n0 + r) * K + kt + cs, lB + buf * 128 * 64 + e);
        }
    };

    int cur = 0;
    if (DB) { STAGE(0, 0); __syncthreads(); }
    for (int kt = 0; kt < K; kt += 64) {
        if (DB) {
            if (kt + 64 < K) STAGE(cur ^ 1, kt + 64);
        } else {
            STAGE(0, kt);
            __syncthreads();
        }
        const char* bA = (const char*)lA + cur * (BM * 128);
        const char* bB = (const char*)lB + cur * (128 * 128);
        bf16x8 af[2][4], bfr[2][NI];
#pragma unroll
        for (int kk = 0; kk < 2; kk++) {
#pragma unroll
            for (int mi = 0; mi < 4; mi++)
                af[kk][mi] = *(const bf16x8*)(bA + swz(wr * 64 + mi * 16 + fr, kk * 64 + g * 16));
#pragma unroll
            for (int ni = 0; ni < NI; ni++)
                bfr[kk][ni] = *(const bf16x8*)(bB + swz(wc * WC + ni * 16 + fr, kk * 64 + g * 16));
        }
#pragma unroll
        for (int kk = 0; kk < 2; kk++)
#pragma unroll
            for (int mi = 0; mi < 4; mi++)
#pragma unroll
                for (int ni = 0; ni < NI; ni++)
                    acc[mi][ni] = __builtin_amdgcn_mfma_f32_16x16x32_bf16(
                        af[kk][mi], bfr[kk][ni], acc[mi][ni], 0, 0, 0);
        __syncthreads();
        if (DB) cur ^= 1;
    }

    if (Cb && !Cf && !resid) {
        // vectorized epilogue: stage to LDS (pitch 136 elems, 272B rows,
        // 16B-aligned, 4-bank rotation/row), then coalesced 16B stores.
        bf16* et = (bf16*)SM;   // safe: final K-loop barrier drained all reads
#pragma unroll
        for (int ni = 0; ni < NI; ni++) {
            const int cl = wc * WC + ni * 16 + fr;
            const float bv = bias ? bias[n0 + cl] : 0.f;
#pragma unroll
            for (int mi = 0; mi < 4; mi++)
#pragma unroll
                for (int r = 0; r < 4; r++) {
                    float v = acc[mi][ni][r] + bv;
                    if (act_gelu) v = 0.5f * v * (1.f + erff(v * 0.70710678118654752f));
                    et[(wr * 64 + mi * 16 + g * 4 + r) * 136 + cl] = (bf16)v;
                }
        }
        __syncthreads();
        const int er = tid >> 4, ec = (tid & 15) * 8;
#pragma unroll
        for (int p = 0; p < BM / 16; p++) {
            const int row = p * 16 + er;
            bf16x8 vv = *(const bf16x8*)&et[row * 136 + ec];
            *(bf16x8*)&Cb[(size_t)(m0 + row) * N + n0 + ec] = vv;
        }
    } else {
#pragma unroll
        for (int ni = 0; ni < NI; ni++) {
            const int col = n0 + wc * WC + ni * 16 + fr;
            const float bv = bias ? bias[col] : 0.f;
#pragma unroll
            for (int mi = 0; mi < 4; mi++) {
#pragma unroll
                for (int r = 0; r < 4; r++) {
                    const int row = m0 + wr * 64 + mi * 16 + g * 4 + r;
                    float v = acc[mi][ni][r] + bv;
                    if (act_gelu) v = 0.5f * v * (1.f + erff(v * 0.70710678118654752f));
                    if (resid) v += resid[(size_t)row * N + col];
                    if (Cb) Cb[(size_t)row * N + col] = (bf16)v;
                    if (Cf) Cf[(size_t)row * N + col] = v;
                }
            }
        }
    }
}

// ---------------------------------------------------------------------------
// Flash attention (round-10 structure). 4 waves x 16 q-rows, KV tiles of 64.
// K staged row-major; V from pre-transposed VT. LDS XOR-swizzled; exp2 domain.
// l-sum via MFMA against all-ones B. Causal mask applied ONLY on the diagonal
// tile (kb == tblk); all earlier tiles are provably unmasked.
// ---------------------------------------------------------------------------
__global__ __launch_bounds__(256) void flash_kernel(
    const bf16* __restrict__ Qb, int qs, const bf16* __restrict__ Kb, int ks,
    const bf16* __restrict__ VT, bf16* __restrict__ Ob, int os,
    float* __restrict__ m_out, float* __restrict__ l_out,
    int T, int S, int causal) {
    __shared__ __align__(16) char Kl[64 * 128];
    __shared__ __align__(16) char Vl[64 * 128];
    __shared__ __align__(16) char Pl[4][16 * 128];

    const int tid = threadIdx.x;
    const int lane = tid & 63, w = tid >> 6;
    const int g = lane >> 4, fr = lane & 15;
    const int gx = gridDim.x;
    const int wg = xcd_chunk(blockIdx.y * gx + blockIdx.x, gx * gridDim.y);
    const int tblk = wg % gx;
    const int bh = wg / gx, b = bh >> 4, h = bh & 15;
    const int t0 = tblk * 64 + w * 16;

    const bf16* Q = Qb + (size_t)h * 64;
    const bf16* K = Kb + (size_t)h * 64;

    bf16x8 qf[2];
    {
        const bf16* qrow = Q + (size_t)(b * T + t0 + fr) * qs + g * 8;
        qf[0] = *(const bf16x8*)(qrow);
        qf[1] = *(const bf16x8*)(qrow + 32);
    }
    bf16x8 onef;
#pragma unroll
    for (int j = 0; j < 8; j++) onef[j] = (bf16)1.f;

    float m_r[4];
    f32x4 lsum;
    f32x4 o[4];
#pragma unroll
    for (int r = 0; r < 4; r++) { m_r[r] = -1e30f; lsum[r] = 0.f; }
#pragma unroll
    for (int d = 0; d < 4; d++)
#pragma unroll
        for (int r = 0; r < 4; r++) o[d][r] = 0.f;

    const int sr = tid >> 3;          // staging row 0..31 (+32 on rep 1)
    const int scc = (tid & 7) * 8;    // staging col (elems)

    const int nkb = causal ? (tblk + 1) : (S >> 6);
    for (int kb = 0; kb < nkb; kb++) {
        const int s0 = kb * 64;
        const bool masked = causal && (kb == tblk);
#pragma unroll
        for (int rep = 0; rep < 2; rep++) {
            int r = sr + rep * 32;
            *(bf16x8*)(Kl + swz(r, scc * 2)) =
                *(const bf16x8*)(K + (size_t)(b * S + s0 + r) * ks + scc);
            *(bf16x8*)(Vl + swz(r, scc * 2)) =
                *(const bf16x8*)(VT + (size_t)(bh * 64 + r) * S + s0 + scc);
        }
        __syncthreads();

        float p[4][4];
#pragma unroll
        for (int sf = 0; sf < 4; sf++) {
            bf16x8 kf0 = *(const bf16x8*)(Kl + swz(sf * 16 + fr, g * 16));
            bf16x8 kf1 = *(const bf16x8*)(Kl + swz(sf * 16 + fr, 64 + g * 16));
            f32x4 sa;
            sa[0] = sa[1] = sa[2] = sa[3] = 0.f;
            sa = __builtin_amdgcn_mfma_f32_16x16x32_bf16(qf[0], kf0, sa, 0, 0, 0);
            sa = __builtin_amdgcn_mfma_f32_16x16x32_bf16(qf[1], kf1, sa, 0, 0, 0);
#pragma unroll
            for (int r = 0; r < 4; r++) {
                float sc = sa[r] * SC2;
                if (masked) {
                    int t = t0 + g * 4 + r, s = s0 + sf * 16 + fr;
                    if (s > t) sc = -1e30f;
                }
                p[sf][r] = sc;
            }
        }
        float mb[4], corr[4];
#pragma unroll
        for (int r = 0; r < 4; r++) {
            mb[r] = fmaxf(fmaxf(p[0][r], p[1][r]), fmaxf(p[2][r], p[3][r]));
            mb[r] = fmaxf(mb[r], __shfl_xor(mb[r], 1));
            mb[r] = fmaxf(mb[r], __shfl_xor(mb[r], 2));
            mb[r] = fmaxf(mb[r], __shfl_xor(mb[r], 4));
            mb[r] = fmaxf(mb[r], __shfl_xor(mb[r], 8));
            float mn = fmaxf(m_r[r], mb[r]);
            corr[r] = exp2f(m_r[r] - mn);
            m_r[r] = mn;
        }
#pragma unroll
        for (int sf = 0; sf < 4; sf++)
#pragma unroll
            for (int r = 0; r < 4; r++)
                p[sf][r] = exp2f(p[sf][r] - m_r[r]);
#pragma unroll
        for (int r = 0; r < 4; r++) lsum[r] *= corr[r];
#pragma unroll
        for (int d = 0; d < 4; d++)
#pragma unroll
            for (int r = 0; r < 4; r++) o[d][r] *= corr[r];
#pragma unroll
        for (int sf = 0; sf < 4; sf++)
#pragma unroll
            for (int r = 0; r < 4; r++)
                *(bf16*)(Pl[w] + swz(g * 4 + r, (sf * 16 + fr) * 2)) = (bf16)p[sf][r];
#pragma unroll
        for (int kc = 0; kc < 2; kc++) {
            bf16x8 pf = *(const bf16x8*)(Pl[w] + swz(fr, kc * 64 + g * 16));
            lsum = __builtin_amdgcn_mfma_f32_16x16x32_bf16(pf, onef, lsum, 0, 0, 0);
#pragma unroll
            for (int d = 0; d < 4; d++) {
                bf16x8 vf = *(const bf16x8*)(Vl + swz(d * 16 + fr, kc * 64 + g * 16));
                o[d] = __builtin_amdgcn_mfma_f32_16x16x32_bf16(pf, vf, o[d], 0, 0, 0);
            }
        }
        __syncthreads();
    }

    float inv[4];
#pragma unroll
    for (int r = 0; r < 4; r++) inv[r] = __builtin_amdgcn_rcpf(lsum[r]);
#pragma unroll
    for (int d = 0; d < 4; d++)
#pragma unroll
        for (int r = 0; r < 4; r++) {
            int t = t0 + g * 4 + r;
            Ob[((size_t)(b * T + t)) * os + h * 64 + d * 16 + fr] =
                (bf16)(o[d][r] * inv[r]);
        }
    if (m_out && fr == 0) {
#pragma unroll
        for (int r = 0; r < 4; r++) {
            int t = t0 + g * 4 + r;
            m_out[((size_t)(b * 16 + h)) * T + t] = m_r[r];   // exp2-scaled units
            l_out[((size_t)(b * 16 + h)) * T + t] = lsum[r];
        }
    }
}

// ---------------------------------------------------------------------------
// Cross-attn probs mean over heads * ||tv||:  out1[b,t,s].  (round-10 version)
// No LDS, no barriers: K/Q fragments loaded directly from global (L2-resident),
// latency hidden by TLP (1024 blocks = 4/CU). 64t x 64s per block, 16-h loop.
// ---------------------------------------------------------------------------
__global__ __launch_bounds__(256) void probsmean_kernel(
    const bf16* __restrict__ Qb, const bf16* __restrict__ Kb,
    const float* __restrict__ m_arr, const float* __restrict__ l_arr,
    const float* __restrict__ norms, float* __restrict__ outw, int T, int S) {
    const int tid = threadIdx.x;
    const int lane = tid & 63, w = tid >> 6;
    const int g = lane >> 4, fr = lane & 15;
    const int flat = (blockIdx.z * gridDim.y + blockIdx.y) * gridDim.x + blockIdx.x;
    const int wg = xcd_chunk(flat, gridDim.x * gridDim.y * gridDim.z);
    const int tblk = wg & 15, sblk = (wg >> 4) & 15, b = wg >> 8;
    const int t0 = tblk * 64 + w * 16;
    const int s0 = sblk * 64;

    float acc[4][4];
#pragma unroll
    for (int sf = 0; sf < 4; sf++)
#pragma unroll
        for (int r = 0; r < 4; r++) acc[sf][r] = 0.f;

    const bf16* qbase = Qb + ((size_t)(b * T + t0 + fr)) * 1024 + g * 8;
    const bf16* kbase = Kb + ((size_t)(b * S + s0 + fr)) * 2048 + g * 8;

    for (int h = 0; h < 16; h++) {
        const int hoff = h * 64;
        bf16x8 qf0 = *(const bf16x8*)(qbase + hoff);
        bf16x8 qf1 = *(const bf16x8*)(qbase + hoff + 32);
        bf16x8 kf0[4], kf1[4];
#pragma unroll
        for (int sf = 0; sf < 4; sf++) {
            const bf16* krow = kbase + (size_t)sf * 16 * 2048 + hoff;
            kf0[sf] = *(const bf16x8*)(krow);
            kf1[sf] = *(const bf16x8*)(krow + 32);
        }
        float mh[4], il[4];
#pragma unroll
        for (int r = 0; r < 4; r++) {
            int t = t0 + g * 4 + r;
            mh[r] = m_arr[((size_t)(b * 16 + h)) * T + t];
            il[r] = __builtin_amdgcn_rcpf(l_arr[((size_t)(b * 16 + h)) * T + t] * 16.f);
        }
#pragma unroll
        for (int sf = 0; sf < 4; sf++) {
            f32x4 sa;
            sa[0] = sa[1] = sa[2] = sa[3] = 0.f;
            sa = __builtin_amdgcn_mfma_f32_16x16x32_bf16(qf0, kf0[sf], sa, 0, 0, 0);
            sa = __builtin_amdgcn_mfma_f32_16x16x32_bf16(qf1, kf1[sf], sa, 0, 0, 0);
#pragma unroll
            for (int r = 0; r < 4; r++)
                acc[sf][r] += exp2f(sa[r] * SC2 - mh[r]) * il[r];
        }
    }
#pragma unroll
    for (int sf = 0; sf < 4; sf++) {
        int s = s0 + sf * 16 + fr;
        float nr = norms[b * S + s];
#pragma unroll
        for (int r = 0; r < 4; r++) {
            int t = t0 + g * 4 + r;
            outw[((size_t)(b * T + t)) * S + s] = acc[sf][r] * nr;
        }
    }
}

// ---------------------------------------------------------------------------
extern "C" void kernel_launch(void* const* d_in, const int* in_sizes, int n_in,
                              void* d_out, int out_size, void* d_ws, size_t ws_size,
                              hipStream_t stream) {
    (void)in_sizes; (void)n_in; (void)out_size; (void)ws_size;
    const float* decoder_input  = (const float*)d_in[0];
    const float* encoder_output = (const float*)d_in[1];
    const float* ln_g   = (const float*)d_in[4];
    const float* ln_b   = (const float*)d_in[5];
    const float* w_in1  = (const float*)d_in[6];
    const float* b_in1  = (const float*)d_in[7];
    const float* w_out1 = (const float*)d_in[8];
    const float* b_out1 = (const float*)d_in[9];
    const float* w_in2  = (const float*)d_in[10];
    const float* b_in2  = (const float*)d_in[11];
    const float* w_out2 = (const float*)d_in[12];
    const float* b_out2 = (const float*)d_in[13];
    const float* mlp_w1 = (const float*)d_in[14];
    const float* mlp_b1 = (const float*)d_in[15];
    const float* mlp_w2 = (const float*)d_in[16];
    const float* mlp_b2 = (const float*)d_in[17];

    char* ws = (char*)d_ws;
    size_t off = 0;
    auto alloc = [&](size_t bytes) {
        char* p = ws + off;
        off += (bytes + 255) & ~(size_t)255;
        return p;
    };
    // Six cvt outputs contiguous (all sizes are 256B multiples -> no padding):
    bf16* W_IN1B   = (bf16*)alloc(3072ULL * 1024 * 2);
    bf16* W_OUT1B  = (bf16*)alloc(1024ULL * 1024 * 2);
    bf16* W_IN2B   = (bf16*)alloc(3072ULL * 1024 * 2);
    bf16* W_OUT2B  = (bf16*)alloc(1024ULL * 1024 * 2);
    bf16* MLPW1B   = (bf16*)alloc(4096ULL * 1024 * 2);
    bf16* MLPW2B   = (bf16*)alloc(4096ULL * 1024 * 2);
    bf16* W_OUT2TB = (bf16*)alloc(1024ULL * 1024 * 2);
    char* REGION_QKV = alloc(4096ULL * 3072 * 2);   // qkv1; later q2 + kv2
    char* REGION_H   = alloc(4096ULL * 4096 * 2);   // de_in_b; later tv(f32); later h
    bf16*  ATTNB  = (bf16*)alloc(4096ULL * 1024 * 2);
    float* XF     = (float*)alloc(4096ULL * 1024 * 4);  // x; later lnx_b
    bf16*  XB     = (bf16*)alloc(4096ULL * 1024 * 2);
    bf16*  ENOUTB = (bf16*)alloc(4096ULL * 1024 * 2);
    float* X2F    = (float*)alloc(4096ULL * 1024 * 4);
    bf16*  VTB    = (bf16*)alloc(64ULL * 64 * 1024 * 2); // V^T per (b,h): 8MB
    float* NORMS  = (float*)alloc(4096 * 4);
    float* MARR   = (float*)alloc(65536ULL * 4);
    float* LARR   = (float*)alloc(65536ULL * 4);

    bf16* QKV1B = (bf16*)REGION_QKV;
    bf16* Q2B   = (bf16*)REGION_QKV;
    bf16* KV2B  = (bf16*)(REGION_QKV + 4096ULL * 1024 * 2);
    bf16* DEINB = (bf16*)REGION_H;
    float* TVF  = (float*)REGION_H;
    bf16* HB    = (bf16*)REGION_H;
    bf16* LNXB  = (bf16*)XF;

    float* out0 = (float*)d_out;
    float* out1 = out0 + 4ULL * 1024 * 1024;

    // fused weight conversions (6 blocks -> contiguous outputs at W_IN1B)
    CvtArgs ca;
    ca.src[0] = w_in1;  ca.src[1] = w_out1; ca.src[2] = w_in2;
    ca.src[3] = w_out2; ca.src[4] = mlp_w1; ca.src[5] = mlp_w2;
    wcvt_kernel<<<16384, 256, 0, stream>>>(ca, W_IN1B);
    transpose_cvt_kernel<<<dim3(32, 32), dim3(32, 8), 0, stream>>>(w_out2, W_OUT2TB);

    // de_in = LN(decoder_input)
    ln_kernel<<<4096, 256, 0, stream>>>(decoder_input, ln_g, ln_b, DEINB);
    // qkv1 = de_in @ w_in1^T + b_in1
    gemm_k<128, 1><<<dim3(24, 32), 256, 0, stream>>>(
        DEINB, W_IN1B, b_in1, nullptr, nullptr, QKV1B, 4096, 3072, 1024, 0);
    // self attention (causal): pre-transpose V, then flash
    transpose_v_kernel<<<dim3(32, 2, 64), dim3(32, 8), 0, stream>>>(
        QKV1B + 2048, 3072, 0, VTB, 1024);
    flash_kernel<<<dim3(16, 64), 256, 0, stream>>>(
        QKV1B, 3072, QKV1B + 1024, 3072, VTB, ATTNB, 1024,
        nullptr, nullptr, 1024, 1024, 1);
    // x = decoder_input + attn @ w_out1^T + b_out1  (write f32 + bf16)
    gemm_k<64, 1><<<dim3(8, 64), 256, 0, stream>>>(
        ATTNB, W_OUT1B, b_out1, decoder_input, XF, XB, 4096, 1024, 1024, 0);
    // en_out = LN(encoder_output)
    ln_kernel<<<4096, 256, 0, stream>>>(encoder_output, ln_g, ln_b, ENOUTB);
    // q2 = x @ wq2^T + bq2 ; kv2 = en_out @ w{k,v}2^T + b{k,v}2
    gemm_k<64, 1><<<dim3(8, 64), 256, 0, stream>>>(
        XB, W_IN2B, b_in2, nullptr, nullptr, Q2B, 4096, 1024, 1024, 0);
    gemm_k<128, 1><<<dim3(16, 32), 256, 0, stream>>>(
        ENOUTB, W_IN2B + 1024ULL * 1024, b_in2 + 1024, nullptr, nullptr, KV2B,
        4096, 2048, 1024, 0);
    // cross attention (stores m,l): pre-transpose V2, then flash
    transpose_v_kernel<<<dim3(32, 2, 64), dim3(32, 8), 0, stream>>>(
        KV2B + 1024, 2048, 0, VTB, 1024);
    flash_kernel<<<dim3(16, 64), 256, 0, stream>>>(
        Q2B, 1024, KV2B, 2048, VTB, ATTNB, 1024, MARR, LARR,
        1024, 1024, 0);
    // x2 = x + attn2 @ w_out2^T + b_out2
    gemm_k<64, 1><<<dim3(8, 64), 256, 0, stream>>>(
        ATTNB, W_OUT2B, b_out2, XF, X2F, nullptr, 4096, 1024, 1024, 0);
    // tv = en_out @ w_out2 (non-transposed) -> row norms
    gemm_k<64, 1><<<dim3(8, 64), 256, 0, stream>>>(
        ENOUTB, W_OUT2TB, nullptr, nullptr, TVF, nullptr, 4096, 1024, 1024, 0);
    rownorm_kernel<<<4096, 256, 0, stream>>>(TVF, NORMS);
    // out1 = mean_h(probs) * ||tv||
    probsmean_kernel<<<dim3(16, 16, 4), 256, 0, stream>>>(
        Q2B, KV2B, MARR, LARR, NORMS, out1, 1024, 1024);
    // mlp
    ln_kernel<<<4096, 256, 0, stream>>>(X2F, ln_g, ln_b, LNXB);
    gemm_k<128, 1><<<dim3(32, 32), 256, 0, stream>>>(
        LNXB, MLPW1B, mlp_b1, nullptr, nullptr, HB, 4096, 4096, 1024, 1);
    gemm_k<64, 1><<<dim3(8, 64), 256, 0, stream>>>(
        HB, MLPW2B, mlp_b2, X2F, out0, nullptr, 4096, 1024, 4096, 0);
}